// Round 3
// baseline (58.241 us; speedup 1.0000x reference)
//
#include <hip/hip_runtime.h>
#include <math.h>

#define BB 4
#define NN 5
#define CC_DIM 64
#define HH 100
#define WW 252
#define HW (HH * WW)
#define CPT 8              // channels per thread
#define NCHUNK (CC_DIM / CPT)  // 8 chunks

__global__ __launch_bounds__(256) void where2comm_fuse_kernel(
    const float* __restrict__ x,    // (B*N, C, H, W)
    const float* __restrict__ ptm,  // (B, N, N, 2, 3)
    float* __restrict__ out)        // (B, C, H, W) + 1 scalar
{
    const int idx = blockIdx.x * blockDim.x + threadIdx.x;
    const int total = BB * NCHUNK * HH * WW;   // 806400
    if (idx >= total) {
        return;
    }

    // decompose: w fastest (coalescing), then h, then channel-chunk, then b
    int w = idx % WW;
    int t = idx / WW;
    int h = t % HH;
    t /= HH;
    int cc = t % NCHUNK;
    int b = t / NCHUNK;

    // normalized grid coords (match reference formulas exactly)
    const float gx = (2.0f * (float)w + 1.0f) / (float)WW - 1.0f;
    const float gy = (2.0f * (float)h + 1.0f) / (float)HH - 1.0f;

    // ---- per-agent sampling params (all 5 up front; cheap VALU) ----
    const float* th_b = ptm + (size_t)b * (NN * NN * 6);
    int   off[NN][4];        // corner byte-element offsets into an HW plane
    float ew[NN][4];         // effective corner weights (weight * validity)
    const float* base[NN];   // per-agent channel-0 plane pointer

#pragma unroll
    for (int n = 0; n < NN; ++n) {
        const float t00 = th_b[n * 6 + 0];
        const float t01 = th_b[n * 6 + 1];
        const float t02 = th_b[n * 6 + 2];
        const float t10 = th_b[n * 6 + 3];
        const float t11 = th_b[n * 6 + 4];
        const float t12 = th_b[n * 6 + 5];

        const float cx = t00 * gx + t01 * gy + t02;
        const float cy = t10 * gx + t11 * gy + t12;

        const float ix = ((cx + 1.0f) * (float)WW - 1.0f) * 0.5f;
        const float iy = ((cy + 1.0f) * (float)HH - 1.0f) * 0.5f;

        const float x0f = floorf(ix);
        const float y0f = floorf(iy);
        const float x1f = x0f + 1.0f;
        const float y1f = y0f + 1.0f;

        const float wx1 = ix - x0f;
        const float wx0 = 1.0f - wx1;
        const float wy1 = iy - y0f;
        const float wy0 = 1.0f - wy1;

        const float mx0 = (x0f >= 0.0f && x0f <= (float)(WW - 1)) ? 1.0f : 0.0f;
        const float mx1 = (x1f >= 0.0f && x1f <= (float)(WW - 1)) ? 1.0f : 0.0f;
        const float my0 = (y0f >= 0.0f && y0f <= (float)(HH - 1)) ? 1.0f : 0.0f;
        const float my1 = (y1f >= 0.0f && y1f <= (float)(HH - 1)) ? 1.0f : 0.0f;

        const int xi0 = (int)fminf(fmaxf(x0f, 0.0f), (float)(WW - 1));
        const int xi1 = (int)fminf(fmaxf(x1f, 0.0f), (float)(WW - 1));
        const int yi0 = (int)fminf(fmaxf(y0f, 0.0f), (float)(HH - 1));
        const int yi1 = (int)fminf(fmaxf(y1f, 0.0f), (float)(HH - 1));

        ew[n][0] = wx0 * wy0 * mx0 * my0;
        ew[n][1] = wx1 * wy0 * mx1 * my0;
        ew[n][2] = wx0 * wy1 * mx0 * my1;
        ew[n][3] = wx1 * wy1 * mx1 * my1;

        off[n][0] = yi0 * WW + xi0;
        off[n][1] = yi0 * WW + xi1;
        off[n][2] = yi1 * WW + xi0;
        off[n][3] = yi1 * WW + xi1;

        base[n] = x + ((size_t)(b * NN + n) * CC_DIM + cc * CPT) * HW;
    }

    float acc[CPT];
#pragma unroll
    for (int c = 0; c < CPT; ++c) acc[c] = -INFINITY;

    // ---- software-pipelined gather: double-buffered 32-load batches ----
    float buf[2][4][CPT];

    // prologue: issue agent 0's loads
#pragma unroll
    for (int c = 0; c < CPT; ++c) {
        const float* pc = base[0] + (size_t)c * HW;
        buf[0][0][c] = pc[off[0][0]];
        buf[0][1][c] = pc[off[0][1]];
        buf[0][2][c] = pc[off[0][2]];
        buf[0][3][c] = pc[off[0][3]];
    }

#pragma unroll
    for (int n = 0; n < NN; ++n) {
        const int cur = n & 1;
        const int nxt = (n + 1) & 1;

        // issue next agent's 32 loads before consuming current batch
        if (n + 1 < NN) {
#pragma unroll
            for (int c = 0; c < CPT; ++c) {
                const float* pc = base[n + 1] + (size_t)c * HW;
                buf[nxt][0][c] = pc[off[n + 1][0]];
                buf[nxt][1][c] = pc[off[n + 1][1]];
                buf[nxt][2][c] = pc[off[n + 1][2]];
                buf[nxt][3][c] = pc[off[n + 1][3]];
            }
        }

        // consume current batch
        const float e00 = ew[n][0], e10 = ew[n][1], e01 = ew[n][2], e11 = ew[n][3];
#pragma unroll
        for (int c = 0; c < CPT; ++c) {
            float v = buf[cur][0][c] * e00;
            v = fmaf(buf[cur][1][c], e10, v);
            v = fmaf(buf[cur][2][c], e01, v);
            v = fmaf(buf[cur][3][c], e11, v);
            acc[c] = fmaxf(acc[c], v);
        }
    }

    // write outputs: out[b, cc*CPT + c, h, w]
#pragma unroll
    for (int c = 0; c < CPT; ++c) {
        out[(((size_t)b * CC_DIM + cc * CPT + c) * HH + h) * WW + w] = acc[c];
    }

    if (idx == 0) {
        out[(size_t)BB * CC_DIM * HW] = 0.0f;  // communication_rates
    }
}

extern "C" void kernel_launch(void* const* d_in, const int* in_sizes, int n_in,
                              void* d_out, int out_size, void* d_ws, size_t ws_size,
                              hipStream_t stream) {
    const float* x = (const float*)d_in[0];
    const float* ptm = (const float*)d_in[3];
    float* out = (float*)d_out;

    const int total = BB * NCHUNK * HH * WW;  // 806400
    const int block = 256;
    const int grid = (total + block - 1) / block;  // 3150
    where2comm_fuse_kernel<<<grid, block, 0, stream>>>(x, ptm, out);
}

// Round 4
// 58.195 us; speedup vs baseline: 1.0008x; 1.0008x over previous
//
#include <hip/hip_runtime.h>
#include <math.h>

#define BB 4
#define NN 5
#define CC_DIM 64
#define HH 100
#define WW 252
#define HW (HH * WW)
#define CPT 8              // channels per thread
#define NCHUNK (CC_DIM / CPT)  // 8 chunks

__global__ __launch_bounds__(256) void where2comm_fuse_kernel(
    const float* __restrict__ x,    // (B*N, C, H, W)
    const float* __restrict__ ptm,  // (B, N, N, 2, 3)
    float* __restrict__ out)        // (B, C, H, W) + 1 scalar
{
    const int idx = blockIdx.x * blockDim.x + threadIdx.x;
    const int total = BB * NCHUNK * HH * WW;   // 806400
    if (idx >= total) {
        return;
    }

    // decompose: w fastest (coalescing), then h, then channel-chunk, then b
    int w = idx % WW;
    int t = idx / WW;
    int h = t % HH;
    t /= HH;
    int cc = t % NCHUNK;
    int b = t / NCHUNK;

    // normalized grid coords (match reference formulas exactly)
    const float gx = (2.0f * (float)w + 1.0f) / (float)WW - 1.0f;
    const float gy = (2.0f * (float)h + 1.0f) / (float)HH - 1.0f;

    // ---- per-agent sampling params (all 5 up front; cheap VALU) ----
    const float* th_b = ptm + (size_t)b * (NN * NN * 6);
    int   off[NN][4];        // corner element offsets into an HW plane
    float ew[NN][4];         // effective corner weights (weight * validity)
    const float* base[NN];   // per-agent channel-0 plane pointer

#pragma unroll
    for (int n = 0; n < NN; ++n) {
        const float t00 = th_b[n * 6 + 0];
        const float t01 = th_b[n * 6 + 1];
        const float t02 = th_b[n * 6 + 2];
        const float t10 = th_b[n * 6 + 3];
        const float t11 = th_b[n * 6 + 4];
        const float t12 = th_b[n * 6 + 5];

        const float cx = t00 * gx + t01 * gy + t02;
        const float cy = t10 * gx + t11 * gy + t12;

        const float ix = ((cx + 1.0f) * (float)WW - 1.0f) * 0.5f;
        const float iy = ((cy + 1.0f) * (float)HH - 1.0f) * 0.5f;

        const float x0f = floorf(ix);
        const float y0f = floorf(iy);
        const float x1f = x0f + 1.0f;
        const float y1f = y0f + 1.0f;

        const float wx1 = ix - x0f;
        const float wx0 = 1.0f - wx1;
        const float wy1 = iy - y0f;
        const float wy0 = 1.0f - wy1;

        const float mx0 = (x0f >= 0.0f && x0f <= (float)(WW - 1)) ? 1.0f : 0.0f;
        const float mx1 = (x1f >= 0.0f && x1f <= (float)(WW - 1)) ? 1.0f : 0.0f;
        const float my0 = (y0f >= 0.0f && y0f <= (float)(HH - 1)) ? 1.0f : 0.0f;
        const float my1 = (y1f >= 0.0f && y1f <= (float)(HH - 1)) ? 1.0f : 0.0f;

        const int xi0 = (int)fminf(fmaxf(x0f, 0.0f), (float)(WW - 1));
        const int xi1 = (int)fminf(fmaxf(x1f, 0.0f), (float)(WW - 1));
        const int yi0 = (int)fminf(fmaxf(y0f, 0.0f), (float)(HH - 1));
        const int yi1 = (int)fminf(fmaxf(y1f, 0.0f), (float)(HH - 1));

        ew[n][0] = wx0 * wy0 * mx0 * my0;
        ew[n][1] = wx1 * wy0 * mx1 * my0;
        ew[n][2] = wx0 * wy1 * mx0 * my1;
        ew[n][3] = wx1 * wy1 * mx0 * my1 * 0.0f + wx1 * wy1 * mx1 * my1;  // keep formula clear below
        ew[n][3] = wx1 * wy1 * mx1 * my1;

        off[n][0] = yi0 * WW + xi0;
        off[n][1] = yi0 * WW + xi1;
        off[n][2] = yi1 * WW + xi0;
        off[n][3] = yi1 * WW + xi1;

        base[n] = x + ((size_t)(b * NN + n) * CC_DIM + cc * CPT) * HW;
    }

    float acc[CPT];
#pragma unroll
    for (int c = 0; c < CPT; ++c) acc[c] = -INFINITY;

    // ---- software-pipelined gather: double-buffered 32-load batches,
    //      pinned with sched_barrier so the compiler cannot sink the
    //      next batch's loads below the current batch's consume ----
    float bufA[4][CPT], bufB[4][CPT];

    // prologue: issue agent 0's loads into bufA
#pragma unroll
    for (int c = 0; c < CPT; ++c) {
        const float* pc = base[0] + (size_t)c * HW;
        bufA[0][c] = pc[off[0][0]];
        bufA[1][c] = pc[off[0][1]];
        bufA[2][c] = pc[off[0][2]];
        bufA[3][c] = pc[off[0][3]];
    }

#define ISSUE(BUF, n)                                                     \
    {                                                                     \
        _Pragma("unroll")                                                 \
        for (int c = 0; c < CPT; ++c) {                                   \
            const float* pc = base[n] + (size_t)c * HW;                   \
            BUF[0][c] = pc[off[n][0]];                                    \
            BUF[1][c] = pc[off[n][1]];                                    \
            BUF[2][c] = pc[off[n][2]];                                    \
            BUF[3][c] = pc[off[n][3]];                                    \
        }                                                                 \
    }

#define CONSUME(BUF, n)                                                   \
    {                                                                     \
        const float e00 = ew[n][0], e10 = ew[n][1];                       \
        const float e01 = ew[n][2], e11 = ew[n][3];                       \
        _Pragma("unroll")                                                 \
        for (int c = 0; c < CPT; ++c) {                                   \
            float v = BUF[0][c] * e00;                                    \
            v = fmaf(BUF[1][c], e10, v);                                  \
            v = fmaf(BUF[2][c], e01, v);                                  \
            v = fmaf(BUF[3][c], e11, v);                                  \
            acc[c] = fmaxf(acc[c], v);                                    \
        }                                                                 \
    }

    // n=0: issue 1 into B, fence, consume A
    ISSUE(bufB, 1);
    __builtin_amdgcn_sched_barrier(0);
    CONSUME(bufA, 0);
    // n=1: issue 2 into A, fence, consume B
    ISSUE(bufA, 2);
    __builtin_amdgcn_sched_barrier(0);
    CONSUME(bufB, 1);
    // n=2: issue 3 into B, fence, consume A
    ISSUE(bufB, 3);
    __builtin_amdgcn_sched_barrier(0);
    CONSUME(bufA, 2);
    // n=3: issue 4 into A, fence, consume B
    ISSUE(bufA, 4);
    __builtin_amdgcn_sched_barrier(0);
    CONSUME(bufB, 3);
    // n=4: consume A
    CONSUME(bufA, 4);

#undef ISSUE
#undef CONSUME

    // write outputs: out[b, cc*CPT + c, h, w]
#pragma unroll
    for (int c = 0; c < CPT; ++c) {
        out[(((size_t)b * CC_DIM + cc * CPT + c) * HH + h) * WW + w] = acc[c];
    }

    if (idx == 0) {
        out[(size_t)BB * CC_DIM * HW] = 0.0f;  // communication_rates
    }
}

extern "C" void kernel_launch(void* const* d_in, const int* in_sizes, int n_in,
                              void* d_out, int out_size, void* d_ws, size_t ws_size,
                              hipStream_t stream) {
    const float* x = (const float*)d_in[0];
    const float* ptm = (const float*)d_in[3];
    float* out = (float*)d_out;

    const int total = BB * NCHUNK * HH * WW;  // 806400
    const int block = 256;
    const int grid = (total + block - 1) / block;  // 3150
    where2comm_fuse_kernel<<<grid, block, 0, stream>>>(x, ptm, out);
}